// Round 1
// baseline (1135.198 us; speedup 1.0000x reference)
//
#include <hip/hip_runtime.h>
#include <hip/hip_bf16.h>
#include <stdint.h>

// Problem constants
#define T_TOK 4096   // B*S
#define H_DIM 1024
#define F_DIM 2816
#define E_NUM 8
#define ROWS_CAP 9216  // 8192 + 8*128 padding headroom

typedef float  f32x4  __attribute__((ext_vector_type(4)));
typedef __bf16 bf16x8 __attribute__((ext_vector_type(8)));

__device__ __forceinline__ unsigned short f32_bf16(float f) {
  union { float f; unsigned u; } v; v.f = f;
  unsigned r = v.u + 0x7fffu + ((v.u >> 16) & 1u);
  return (unsigned short)(r >> 16);
}

__device__ __forceinline__ void async16(const void* g, void* l) {
  __builtin_amdgcn_global_load_lds(
      (__attribute__((address_space(1))) void*)(g),
      (__attribute__((address_space(3))) void*)(l),
      16, 0, 0);
}

__device__ __forceinline__ f32x4 mfma16(bf16x8 a, bf16x8 b, f32x4 c) {
  return __builtin_amdgcn_mfma_f32_16x16x32_bf16(a, b, c, 0, 0, 0);
}

// ---------------- converts ----------------

// x fp32 [T,H] -> bf16 [T,H]
__global__ __launch_bounds__(256) void conv_x_kernel(const float* __restrict__ x,
                                                     unsigned short* __restrict__ xb) {
  int i = blockIdx.x * 256 + threadIdx.x;   // one float4 per thread
  float4 v = ((const float4*)x)[i];
  ushort4 o;
  o.x = f32_bf16(v.x); o.y = f32_bf16(v.y); o.z = f32_bf16(v.z); o.w = f32_bf16(v.w);
  ((ushort4*)xb)[i] = o;
}

// src [e][R][C] fp32 -> dst [e][C][R] bf16 (transpose + convert)
__global__ __launch_bounds__(256) void transpose_conv(const float* __restrict__ src,
                                                      unsigned short* __restrict__ dst,
                                                      int R, int C) {
  __shared__ float tile[32][33];
  int e = blockIdx.z;
  const float* s = src + (size_t)e * R * C;
  unsigned short* d = dst + (size_t)e * R * C;
  int r0 = blockIdx.y * 32, c0 = blockIdx.x * 32;
  int tx = threadIdx.x, ty = threadIdx.y;  // 32 x 8
#pragma unroll
  for (int k = 0; k < 4; k++)
    tile[ty + 8 * k][tx] = s[(size_t)(r0 + ty + 8 * k) * C + (c0 + tx)];
  __syncthreads();
#pragma unroll
  for (int k = 0; k < 4; k++)
    d[(size_t)(c0 + ty + 8 * k) * R + (r0 + tx)] = f32_bf16(tile[tx][ty + 8 * k]);
}

// ---------------- router ----------------

__global__ __launch_bounds__(256) void router_kernel(const float* __restrict__ x,
                                                     const float* __restrict__ rw,
                                                     int* __restrict__ t2i,
                                                     float* __restrict__ t2w,
                                                     int* __restrict__ counts,
                                                     float* __restrict__ psum) {
  __shared__ float srw[E_NUM * H_DIM];  // 32 KB
  __shared__ float sP[E_NUM];
  __shared__ int sC[E_NUM];
  int tid = threadIdx.x;
  for (int i = tid; i < E_NUM * H_DIM; i += 256) srw[i] = rw[i];
  if (tid < E_NUM) { sP[tid] = 0.f; sC[tid] = 0; }
  __syncthreads();
  int w = tid >> 6, lane = tid & 63;
  for (int it = 0; it < 16; ++it) {
    int t = blockIdx.x * 64 + w * 16 + it;
    float acc[E_NUM];
#pragma unroll
    for (int e = 0; e < E_NUM; e++) acc[e] = 0.f;
    const float* xr = x + (size_t)t * H_DIM;
    for (int h = lane; h < H_DIM; h += 64) {
      float xv = xr[h];
#pragma unroll
      for (int e = 0; e < E_NUM; e++) acc[e] += xv * srw[e * H_DIM + h];
    }
#pragma unroll
    for (int e = 0; e < E_NUM; e++) {
      float v = acc[e];
      for (int o = 32; o > 0; o >>= 1) v += __shfl_down(v, o, 64);
      acc[e] = __shfl(v, 0, 64);
    }
    if (lane == 0) {
      float mx = acc[0];
#pragma unroll
      for (int e = 1; e < E_NUM; e++) mx = fmaxf(mx, acc[e]);
      float pr[E_NUM], s = 0.f;
#pragma unroll
      for (int e = 0; e < E_NUM; e++) { pr[e] = __expf(acc[e] - mx); s += pr[e]; }
      float inv = 1.f / s;
#pragma unroll
      for (int e = 0; e < E_NUM; e++) atomicAdd(&sP[e], pr[e] * inv);
      int i0 = 0; float v0 = acc[0];
#pragma unroll
      for (int e = 1; e < E_NUM; e++) if (acc[e] > v0) { v0 = acc[e]; i0 = e; }
      int i1 = -1; float v1 = -3.4e38f;
#pragma unroll
      for (int e = 0; e < E_NUM; e++) if (e != i0 && acc[e] > v1) { v1 = acc[e]; i1 = e; }
      float e1 = __expf(v1 - v0);
      float w0 = 1.f / (1.f + e1);
      t2i[2 * t] = i0; t2i[2 * t + 1] = i1;
      t2w[2 * t] = w0; t2w[2 * t + 1] = e1 * w0;
      atomicAdd(&sC[i0], 1); atomicAdd(&sC[i1], 1);
    }
  }
  __syncthreads();
  if (tid < E_NUM) { atomicAdd(&counts[tid], sC[tid]); atomicAdd(&psum[tid], sP[tid]); }
}

__global__ void scan_aux_kernel(const int* __restrict__ counts, const float* __restrict__ psum,
                                int* __restrict__ offsets, int* __restrict__ cursors,
                                float* __restrict__ aux_out) {
  if (threadIdx.x == 0 && blockIdx.x == 0) {
    int off = 0; float aux = 0.f;
    for (int e = 0; e < E_NUM; e++) {
      offsets[e] = off;
      cursors[e] = off;
      off += (counts[e] + 127) & ~127;
      aux += ((float)counts[e] / 8192.0f) * (psum[e] / 4096.0f);
    }
    offsets[E_NUM] = off;
    *aux_out = 8.0f * aux;
  }
}

__global__ __launch_bounds__(256) void assign_kernel(const int* __restrict__ t2i,
                                                     const float* __restrict__ t2w,
                                                     int* __restrict__ cursors,
                                                     int* __restrict__ row2token,
                                                     float* __restrict__ roww) {
  int t = blockIdx.x * 256 + threadIdx.x;
#pragma unroll
  for (int s = 0; s < 2; s++) {
    int e = t2i[2 * t + s];
    int p = atomicAdd(&cursors[e], 1);
    row2token[p] = t;
    roww[p] = t2w[2 * t + s];
  }
}

// ---------------- fused gate/up GEMM ----------------
// act[row, f] = silu(x@Wg) * (x@Wu), bf16.  Tile: BM=128, BN=64, BK=32.
// A: xb [T,H] (k-contig). B: Wgt/Wut [E][F][H] (k-contig, pre-transposed).
__global__ __launch_bounds__(256) void gateup_kernel(
    const unsigned short* __restrict__ xb,
    const unsigned short* __restrict__ wgt,
    const unsigned short* __restrict__ wut,
    unsigned short* __restrict__ act,
    const int* __restrict__ counts, const int* __restrict__ offsets,
    const int* __restrict__ row2token) {
  int e = blockIdx.z;
  int cnt = counts[e];
  int mtile = blockIdx.x;
  if (mtile * 128 >= cnt) return;
  int ntile = blockIdx.y;  // F/64 = 44
  int off = offsets[e];

  __shared__ __align__(16) unsigned short smA[128 * 32];
  __shared__ __align__(16) unsigned short smG[64 * 32];
  __shared__ __align__(16) unsigned short smU[64 * 32];

  int tid = threadIdx.x;
  int w = tid >> 6, lane = tid & 63;
  int wm = w & 1, wn = w >> 1;  // wave tile 64x32 within 128x64

  // staging assignments (16B chunks)
  int cA0 = w * 64 + lane;          // A chunks [0,256)
  int rA0 = cA0 >> 2, qA0 = cA0 & 3;
  int rA1 = rA0 + 64;               // A chunks [256,512)
  int rowbase = mtile * 128;
  int tok0 = (rowbase + rA0 < cnt) ? row2token[off + rowbase + rA0] : 0;
  int tok1 = (rowbase + rA1 < cnt) ? row2token[off + rowbase + rA1] : 0;
  const unsigned short* gA0 = xb + (size_t)tok0 * H_DIM + qA0 * 8;
  const unsigned short* gA1 = xb + (size_t)tok1 * H_DIM + qA0 * 8;
  size_t wb = (size_t)e * F_DIM * H_DIM;
  int rB = cA0 >> 2, qB = cA0 & 3;  // B chunks [0,256): 64 rows
  const unsigned short* gG = wgt + wb + (size_t)(ntile * 64 + rB) * H_DIM + qB * 8;
  const unsigned short* gU = wut + wb + (size_t)(ntile * 64 + rB) * H_DIM + qB * 8;
  unsigned short* lA0 = smA + (w * 64) * 8;
  unsigned short* lA1 = smA + (256 + w * 64) * 8;
  unsigned short* lG = smG + (w * 64) * 8;
  unsigned short* lU = smU + (w * 64) * 8;

  f32x4 accg[4][2], accu[4][2];
#pragma unroll
  for (int i = 0; i < 4; i++)
#pragma unroll
    for (int j = 0; j < 2; j++) {
      accg[i][j] = (f32x4){0.f, 0.f, 0.f, 0.f};
      accu[i][j] = (f32x4){0.f, 0.f, 0.f, 0.f};
    }

  int m = lane & 15, quad = lane >> 4;
  for (int k0 = 0; k0 < H_DIM; k0 += 32) {
    async16(gA0 + k0, lA0);
    async16(gA1 + k0, lA1);
    async16(gG + k0, lG);
    async16(gU + k0, lU);
    __syncthreads();
    bf16x8 a[4], bg[2], bu[2];
#pragma unroll
    for (int i = 0; i < 4; i++)
      a[i] = *(const bf16x8*)(smA + (wm * 64 + 16 * i + m) * 32 + quad * 8);
#pragma unroll
    for (int j = 0; j < 2; j++) {
      bg[j] = *(const bf16x8*)(smG + (wn * 32 + 16 * j + m) * 32 + quad * 8);
      bu[j] = *(const bf16x8*)(smU + (wn * 32 + 16 * j + m) * 32 + quad * 8);
    }
#pragma unroll
    for (int i = 0; i < 4; i++)
#pragma unroll
      for (int j = 0; j < 2; j++) {
        accg[i][j] = mfma16(a[i], bg[j], accg[i][j]);
        accu[i][j] = mfma16(a[i], bu[j], accu[i][j]);
      }
    __syncthreads();
  }

  // epilogue: act = silu(g)*u
#pragma unroll
  for (int i = 0; i < 4; i++)
#pragma unroll
    for (int j = 0; j < 2; j++)
#pragma unroll
      for (int r = 0; r < 4; r++) {
        int rt = wm * 64 + 16 * i + quad * 4 + r;
        int ct = wn * 32 + 16 * j + m;
        float g = accg[i][j][r], u = accu[i][j][r];
        float sv = g / (1.f + __expf(-g)) * u;
        act[(size_t)(off + rowbase + rt) * F_DIM + ntile * 64 + ct] = f32_bf16(sv);
      }
}

// ---------------- down GEMM + weighted scatter ----------------
// out[tok, h] += w_row * (act @ Wd). Tile: BM=128, BN=128, BK=32.
__global__ __launch_bounds__(256) void down_kernel(
    const unsigned short* __restrict__ act,
    const unsigned short* __restrict__ wdt,   // [E][H][F] k-contig
    const int* __restrict__ counts, const int* __restrict__ offsets,
    const int* __restrict__ row2token, const float* __restrict__ roww,
    float* __restrict__ out) {
  int e = blockIdx.z;
  int cnt = counts[e];
  int mtile = blockIdx.x;
  if (mtile * 128 >= cnt) return;
  int ntile = blockIdx.y;  // H/128 = 8
  int off = offsets[e];

  __shared__ __align__(16) unsigned short smA[128 * 32];
  __shared__ __align__(16) unsigned short smB[128 * 32];

  int tid = threadIdx.x;
  int w = tid >> 6, lane = tid & 63;
  int wm = w & 1, wn = w >> 1;  // wave tile 64x64

  int c0 = w * 64 + lane;
  int r0 = c0 >> 2, q0 = c0 & 3;
  int r1 = r0 + 64;
  int rowbase = mtile * 128;
  const unsigned short* gA0 = act + (size_t)(off + rowbase + r0) * F_DIM + q0 * 8;
  const unsigned short* gA1 = act + (size_t)(off + rowbase + r1) * F_DIM + q0 * 8;
  size_t wb = (size_t)e * H_DIM * F_DIM;
  const unsigned short* gB0 = wdt + wb + (size_t)(ntile * 128 + r0) * F_DIM + q0 * 8;
  const unsigned short* gB1 = wdt + wb + (size_t)(ntile * 128 + r1) * F_DIM + q0 * 8;
  unsigned short* lA0 = smA + (w * 64) * 8;
  unsigned short* lA1 = smA + (256 + w * 64) * 8;
  unsigned short* lB0 = smB + (w * 64) * 8;
  unsigned short* lB1 = smB + (256 + w * 64) * 8;

  f32x4 acc[4][4];
#pragma unroll
  for (int i = 0; i < 4; i++)
#pragma unroll
    for (int j = 0; j < 4; j++) acc[i][j] = (f32x4){0.f, 0.f, 0.f, 0.f};

  int m = lane & 15, quad = lane >> 4;
  for (int k0 = 0; k0 < F_DIM; k0 += 32) {
    async16(gA0 + k0, lA0);
    async16(gA1 + k0, lA1);
    async16(gB0 + k0, lB0);
    async16(gB1 + k0, lB1);
    __syncthreads();
    bf16x8 a[4], b[4];
#pragma unroll
    for (int i = 0; i < 4; i++) {
      a[i] = *(const bf16x8*)(smA + (wm * 64 + 16 * i + m) * 32 + quad * 8);
      b[i] = *(const bf16x8*)(smB + (wn * 64 + 16 * i + m) * 32 + quad * 8);
    }
#pragma unroll
    for (int i = 0; i < 4; i++)
#pragma unroll
      for (int j = 0; j < 4; j++) acc[i][j] = mfma16(a[i], b[j], acc[i][j]);
    __syncthreads();
  }

#pragma unroll
  for (int i = 0; i < 4; i++)
#pragma unroll
    for (int r = 0; r < 4; r++) {
      int rt = wm * 64 + 16 * i + quad * 4 + r;
      int lrow = rowbase + rt;
      if (lrow < cnt) {
        int t = row2token[off + lrow];
        float cw = roww[off + lrow];
#pragma unroll
        for (int j = 0; j < 4; j++) {
          int h = ntile * 128 + wn * 64 + 16 * j + m;
          atomicAdd(out + (size_t)t * H_DIM + h, cw * acc[i][j][r]);
        }
      }
    }
}

// ---------------- host ----------------

extern "C" void kernel_launch(void* const* d_in, const int* in_sizes, int n_in,
                              void* d_out, int out_size, void* d_ws, size_t ws_size,
                              hipStream_t stream) {
  const float* x  = (const float*)d_in[0];
  const float* rw = (const float*)d_in[1];
  const float* wg = (const float*)d_in[2];
  const float* wu = (const float*)d_in[3];
  const float* wd = (const float*)d_in[4];
  float* out = (float*)d_out;

  char* ws = (char*)d_ws;
  size_t p = 0;
  auto alloc = [&](size_t bytes) {
    char* r = ws + p;
    p = (p + bytes + 255) & ~(size_t)255;
    return r;
  };
  unsigned short* Xb  = (unsigned short*)alloc((size_t)T_TOK * H_DIM * 2);
  unsigned short* Wgt = (unsigned short*)alloc((size_t)E_NUM * F_DIM * H_DIM * 2);
  unsigned short* Wut = (unsigned short*)alloc((size_t)E_NUM * F_DIM * H_DIM * 2);
  unsigned short* Wdt = (unsigned short*)alloc((size_t)E_NUM * H_DIM * F_DIM * 2);
  unsigned short* Act = (unsigned short*)alloc((size_t)ROWS_CAP * F_DIM * 2);
  int*   t2i = (int*)alloc(T_TOK * 2 * 4);
  float* t2w = (float*)alloc(T_TOK * 2 * 4);
  int*   row2token = (int*)alloc(ROWS_CAP * 4);
  float* roww = (float*)alloc(ROWS_CAP * 4);
  int* ctrs = (int*)alloc(64 * 4);
  int* counts  = ctrs;        // 8
  int* cursors = ctrs + 8;    // 8
  float* psum  = (float*)(ctrs + 16);  // 8
  int* offsets = ctrs + 24;   // 9

  hipMemsetAsync(out, 0, (size_t)T_TOK * H_DIM * 4, stream);
  hipMemsetAsync(ctrs, 0, 96, stream);

  conv_x_kernel<<<T_TOK * H_DIM / 4 / 256, 256, 0, stream>>>(x, Xb);
  transpose_conv<<<dim3(F_DIM / 32, H_DIM / 32, E_NUM), dim3(32, 8), 0, stream>>>(wg, Wgt, H_DIM, F_DIM);
  transpose_conv<<<dim3(F_DIM / 32, H_DIM / 32, E_NUM), dim3(32, 8), 0, stream>>>(wu, Wut, H_DIM, F_DIM);
  transpose_conv<<<dim3(H_DIM / 32, F_DIM / 32, E_NUM), dim3(32, 8), 0, stream>>>(wd, Wdt, F_DIM, H_DIM);

  router_kernel<<<T_TOK / 64, 256, 0, stream>>>(x, rw, t2i, t2w, counts, psum);
  scan_aux_kernel<<<1, 64, 0, stream>>>(counts, psum, offsets, cursors, out + (size_t)T_TOK * H_DIM);
  assign_kernel<<<T_TOK / 256, 256, 0, stream>>>(t2i, t2w, cursors, row2token, roww);

  gateup_kernel<<<dim3(32, F_DIM / 64, E_NUM), 256, 0, stream>>>(Xb, Wgt, Wut, Act, counts, offsets, row2token);
  down_kernel<<<dim3(32, H_DIM / 128, E_NUM), 256, 0, stream>>>(Act, Wdt, counts, offsets, row2token, roww, out);
}

// Round 2
// 721.326 us; speedup vs baseline: 1.5738x; 1.5738x over previous
//
#include <hip/hip_runtime.h>
#include <hip/hip_bf16.h>
#include <stdint.h>

// Problem constants
#define T_TOK 4096   // B*S
#define H_DIM 1024
#define F_DIM 2816
#define E_NUM 8
#define ROWS_CAP 9216   // 8192 + 8*128 padding headroom
#define TOTAL_MT 72     // ROWS_CAP / 128

typedef float  f32x4  __attribute__((ext_vector_type(4)));
typedef __bf16 bf16x8 __attribute__((ext_vector_type(8)));

__device__ __forceinline__ unsigned short f32_bf16(float f) {
  union { float f; unsigned u; } v; v.f = f;
  unsigned r = v.u + 0x7fffu + ((v.u >> 16) & 1u);
  return (unsigned short)(r >> 16);
}

__device__ __forceinline__ void async16(const void* g, void* l) {
  __builtin_amdgcn_global_load_lds(
      (__attribute__((address_space(1))) void*)(g),
      (__attribute__((address_space(3))) void*)(l),
      16, 0, 0);
}

__device__ __forceinline__ f32x4 mfma16(bf16x8 a, bf16x8 b, f32x4 c) {
  return __builtin_amdgcn_mfma_f32_16x16x32_bf16(a, b, c, 0, 0, 0);
}

// ---------------- converts ----------------

// x fp32 [T,H] -> bf16 [T,H]
__global__ __launch_bounds__(256) void conv_x_kernel(const float* __restrict__ x,
                                                     unsigned short* __restrict__ xb) {
  int i = blockIdx.x * 256 + threadIdx.x;   // one float4 per thread
  float4 v = ((const float4*)x)[i];
  ushort4 o;
  o.x = f32_bf16(v.x); o.y = f32_bf16(v.y); o.z = f32_bf16(v.z); o.w = f32_bf16(v.w);
  ((ushort4*)xb)[i] = o;
}

// src [e][R][C] fp32 -> dst [e][C][R] bf16 (transpose + convert)
__global__ __launch_bounds__(256) void transpose_conv(const float* __restrict__ src,
                                                      unsigned short* __restrict__ dst,
                                                      int R, int C) {
  __shared__ float tile[32][33];
  int e = blockIdx.z;
  const float* s = src + (size_t)e * R * C;
  unsigned short* d = dst + (size_t)e * R * C;
  int r0 = blockIdx.y * 32, c0 = blockIdx.x * 32;
  int tx = threadIdx.x, ty = threadIdx.y;  // 32 x 8
#pragma unroll
  for (int k = 0; k < 4; k++)
    tile[ty + 8 * k][tx] = s[(size_t)(r0 + ty + 8 * k) * C + (c0 + tx)];
  __syncthreads();
#pragma unroll
  for (int k = 0; k < 4; k++)
    d[(size_t)(c0 + ty + 8 * k) * R + (r0 + tx)] = f32_bf16(tile[tx][ty + 8 * k]);
}

// ---------------- router ----------------

__global__ __launch_bounds__(256) void router_kernel(const float* __restrict__ x,
                                                     const float* __restrict__ rw,
                                                     int* __restrict__ t2i,
                                                     float* __restrict__ t2w,
                                                     int* __restrict__ counts,
                                                     float* __restrict__ psum) {
  __shared__ float srw[E_NUM * H_DIM];  // 32 KB
  __shared__ float sP[E_NUM];
  __shared__ int sC[E_NUM];
  int tid = threadIdx.x;
  for (int i = tid; i < E_NUM * H_DIM; i += 256) srw[i] = rw[i];
  if (tid < E_NUM) { sP[tid] = 0.f; sC[tid] = 0; }
  __syncthreads();
  int w = tid >> 6, lane = tid & 63;
  for (int it = 0; it < 16; ++it) {
    int t = blockIdx.x * 64 + w * 16 + it;
    float acc[E_NUM];
#pragma unroll
    for (int e = 0; e < E_NUM; e++) acc[e] = 0.f;
    const float* xr = x + (size_t)t * H_DIM;
    for (int h = lane; h < H_DIM; h += 64) {
      float xv = xr[h];
#pragma unroll
      for (int e = 0; e < E_NUM; e++) acc[e] += xv * srw[e * H_DIM + h];
    }
#pragma unroll
    for (int e = 0; e < E_NUM; e++) {
      float v = acc[e];
      for (int o = 32; o > 0; o >>= 1) v += __shfl_down(v, o, 64);
      acc[e] = __shfl(v, 0, 64);
    }
    if (lane == 0) {
      float mx = acc[0];
#pragma unroll
      for (int e = 1; e < E_NUM; e++) mx = fmaxf(mx, acc[e]);
      float pr[E_NUM], s = 0.f;
#pragma unroll
      for (int e = 0; e < E_NUM; e++) { pr[e] = __expf(acc[e] - mx); s += pr[e]; }
      float inv = 1.f / s;
#pragma unroll
      for (int e = 0; e < E_NUM; e++) atomicAdd(&sP[e], pr[e] * inv);
      int i0 = 0; float v0 = acc[0];
#pragma unroll
      for (int e = 1; e < E_NUM; e++) if (acc[e] > v0) { v0 = acc[e]; i0 = e; }
      int i1 = -1; float v1 = -3.4e38f;
#pragma unroll
      for (int e = 0; e < E_NUM; e++) if (e != i0 && acc[e] > v1) { v1 = acc[e]; i1 = e; }
      float e1 = __expf(v1 - v0);
      float w0 = 1.f / (1.f + e1);
      t2i[2 * t] = i0; t2i[2 * t + 1] = i1;
      t2w[2 * t] = w0; t2w[2 * t + 1] = e1 * w0;
      atomicAdd(&sC[i0], 1); atomicAdd(&sC[i1], 1);
    }
  }
  __syncthreads();
  if (tid < E_NUM) { atomicAdd(&counts[tid], sC[tid]); atomicAdd(&psum[tid], sP[tid]); }
}

__global__ void scan_aux_kernel(const int* __restrict__ counts, const float* __restrict__ psum,
                                int* __restrict__ offsets, int* __restrict__ cursors,
                                float* __restrict__ aux_out) {
  if (threadIdx.x == 0 && blockIdx.x == 0) {
    int off = 0; float aux = 0.f;
    for (int e = 0; e < E_NUM; e++) {
      offsets[e] = off;
      cursors[e] = off;
      off += (counts[e] + 127) & ~127;
      aux += ((float)counts[e] / 8192.0f) * (psum[e] / 4096.0f);
    }
    offsets[E_NUM] = off;
    *aux_out = 8.0f * aux;
  }
}

__global__ __launch_bounds__(256) void assign_kernel(const int* __restrict__ t2i,
                                                     const float* __restrict__ t2w,
                                                     int* __restrict__ cursors,
                                                     int* __restrict__ row2token,
                                                     float* __restrict__ roww) {
  int t = blockIdx.x * 256 + threadIdx.x;
#pragma unroll
  for (int s = 0; s < 2; s++) {
    int e = t2i[2 * t + s];
    int p = atomicAdd(&cursors[e], 1);
    row2token[p] = t;
    roww[p] = t2w[2 * t + s];
  }
}

// Map a global (padded) row-tile index to its expert via offsets[].
// offsets[] are 128-aligned cumulative; returns -1 if tile is beyond all rows.
__device__ __forceinline__ int find_expert(const int* __restrict__ offsets, int row0,
                                           int& off_out) {
  int esel = -1, off = 0;
#pragma unroll
  for (int e = 0; e < E_NUM; e++) {
    int lo = offsets[e], hi = offsets[e + 1];
    if (row0 >= lo && row0 < hi) { esel = e; off = lo; }
  }
  off_out = off;
  return esel;
}

// ---------------- fused gate/up GEMM ----------------
// act[row, f] = silu(x@Wg) * (x@Wu), bf16.  Tile: BM=128, BN=64, BK=32.
// Grid: (TOTAL_MT global row-tiles, F/64 ntiles). Row-tiles are dense across
// experts (offsets 128-aligned) -> no dead-block CU starvation.
__global__ __launch_bounds__(256) void gateup_kernel(
    const unsigned short* __restrict__ xb,
    const unsigned short* __restrict__ wgt,
    const unsigned short* __restrict__ wut,
    unsigned short* __restrict__ act,
    const int* __restrict__ counts, const int* __restrict__ offsets,
    const int* __restrict__ row2token) {
  int g = blockIdx.x;
  int row0 = g * 128;
  int off;
  int e = find_expert(offsets, row0, off);
  if (e < 0) return;
  int cnt = counts[e];
  int rowbase = row0 - off;   // row-tile base within this expert
  int ntile = blockIdx.y;     // F/64 = 44

  __shared__ __align__(16) unsigned short smA[128 * 32];
  __shared__ __align__(16) unsigned short smG[64 * 32];
  __shared__ __align__(16) unsigned short smU[64 * 32];

  int tid = threadIdx.x;
  int w = tid >> 6, lane = tid & 63;
  int wm = w & 1, wn = w >> 1;  // wave tile 64x32 within 128x64

  // staging assignments (16B chunks)
  int cA0 = w * 64 + lane;          // A chunks [0,256)
  int rA0 = cA0 >> 2, qA0 = cA0 & 3;
  int rA1 = rA0 + 64;               // A chunks [256,512)
  int tok0 = (rowbase + rA0 < cnt) ? row2token[off + rowbase + rA0] : 0;
  int tok1 = (rowbase + rA1 < cnt) ? row2token[off + rowbase + rA1] : 0;
  const unsigned short* gA0 = xb + (size_t)tok0 * H_DIM + qA0 * 8;
  const unsigned short* gA1 = xb + (size_t)tok1 * H_DIM + qA0 * 8;
  size_t wb = (size_t)e * F_DIM * H_DIM;
  int rB = cA0 >> 2, qB = cA0 & 3;  // B chunks [0,256): 64 rows
  const unsigned short* gG = wgt + wb + (size_t)(ntile * 64 + rB) * H_DIM + qB * 8;
  const unsigned short* gU = wut + wb + (size_t)(ntile * 64 + rB) * H_DIM + qB * 8;
  unsigned short* lA0 = smA + (w * 64) * 8;
  unsigned short* lA1 = smA + (256 + w * 64) * 8;
  unsigned short* lG = smG + (w * 64) * 8;
  unsigned short* lU = smU + (w * 64) * 8;

  f32x4 accg[4][2], accu[4][2];
#pragma unroll
  for (int i = 0; i < 4; i++)
#pragma unroll
    for (int j = 0; j < 2; j++) {
      accg[i][j] = (f32x4){0.f, 0.f, 0.f, 0.f};
      accu[i][j] = (f32x4){0.f, 0.f, 0.f, 0.f};
    }

  int m = lane & 15, quad = lane >> 4;
  for (int k0 = 0; k0 < H_DIM; k0 += 32) {
    async16(gA0 + k0, lA0);
    async16(gA1 + k0, lA1);
    async16(gG + k0, lG);
    async16(gU + k0, lU);
    __syncthreads();
    bf16x8 a[4], bg[2], bu[2];
#pragma unroll
    for (int i = 0; i < 4; i++)
      a[i] = *(const bf16x8*)(smA + (wm * 64 + 16 * i + m) * 32 + quad * 8);
#pragma unroll
    for (int j = 0; j < 2; j++) {
      bg[j] = *(const bf16x8*)(smG + (wn * 32 + 16 * j + m) * 32 + quad * 8);
      bu[j] = *(const bf16x8*)(smU + (wn * 32 + 16 * j + m) * 32 + quad * 8);
    }
#pragma unroll
    for (int i = 0; i < 4; i++)
#pragma unroll
      for (int j = 0; j < 2; j++) {
        accg[i][j] = mfma16(a[i], bg[j], accg[i][j]);
        accu[i][j] = mfma16(a[i], bu[j], accu[i][j]);
      }
    __syncthreads();
  }

  // epilogue: act = silu(g)*u
#pragma unroll
  for (int i = 0; i < 4; i++)
#pragma unroll
    for (int j = 0; j < 2; j++)
#pragma unroll
      for (int r = 0; r < 4; r++) {
        int rt = wm * 64 + 16 * i + quad * 4 + r;
        int ct = wn * 32 + 16 * j + m;
        float g2 = accg[i][j][r], u = accu[i][j][r];
        float sv = g2 / (1.f + __expf(-g2)) * u;
        act[(size_t)(off + rowbase + rt) * F_DIM + ntile * 64 + ct] = f32_bf16(sv);
      }
}

// ---------------- down GEMM + weighted scatter ----------------
// out[tok, h] += w_row * (act @ Wd). Tile: BM=128, BN=128, BK=32.
// Grid: (TOTAL_MT global row-tiles, H/128 ntiles).
__global__ __launch_bounds__(256) void down_kernel(
    const unsigned short* __restrict__ act,
    const unsigned short* __restrict__ wdt,   // [E][H][F] k-contig
    const int* __restrict__ counts, const int* __restrict__ offsets,
    const int* __restrict__ row2token, const float* __restrict__ roww,
    float* __restrict__ out) {
  int g = blockIdx.x;
  int row0 = g * 128;
  int off;
  int e = find_expert(offsets, row0, off);
  if (e < 0) return;
  int cnt = counts[e];
  int rowbase = row0 - off;
  int ntile = blockIdx.y;  // H/128 = 8

  __shared__ __align__(16) unsigned short smA[128 * 32];
  __shared__ __align__(16) unsigned short smB[128 * 32];

  int tid = threadIdx.x;
  int w = tid >> 6, lane = tid & 63;
  int wm = w & 1, wn = w >> 1;  // wave tile 64x64

  int c0 = w * 64 + lane;
  int r0 = c0 >> 2, q0 = c0 & 3;
  int r1 = r0 + 64;
  const unsigned short* gA0 = act + (size_t)(off + rowbase + r0) * F_DIM + q0 * 8;
  const unsigned short* gA1 = act + (size_t)(off + rowbase + r1) * F_DIM + q0 * 8;
  size_t wb = (size_t)e * H_DIM * F_DIM;
  const unsigned short* gB0 = wdt + wb + (size_t)(ntile * 128 + r0) * F_DIM + q0 * 8;
  const unsigned short* gB1 = wdt + wb + (size_t)(ntile * 128 + r1) * F_DIM + q0 * 8;
  unsigned short* lA0 = smA + (w * 64) * 8;
  unsigned short* lA1 = smA + (256 + w * 64) * 8;
  unsigned short* lB0 = smB + (w * 64) * 8;
  unsigned short* lB1 = smB + (256 + w * 64) * 8;

  f32x4 acc[4][4];
#pragma unroll
  for (int i = 0; i < 4; i++)
#pragma unroll
    for (int j = 0; j < 4; j++) acc[i][j] = (f32x4){0.f, 0.f, 0.f, 0.f};

  int m = lane & 15, quad = lane >> 4;
  for (int k0 = 0; k0 < F_DIM; k0 += 32) {
    async16(gA0 + k0, lA0);
    async16(gA1 + k0, lA1);
    async16(gB0 + k0, lB0);
    async16(gB1 + k0, lB1);
    __syncthreads();
    bf16x8 a[4], b[4];
#pragma unroll
    for (int i = 0; i < 4; i++) {
      a[i] = *(const bf16x8*)(smA + (wm * 64 + 16 * i + m) * 32 + quad * 8);
      b[i] = *(const bf16x8*)(smB + (wn * 64 + 16 * i + m) * 32 + quad * 8);
    }
#pragma unroll
    for (int i = 0; i < 4; i++)
#pragma unroll
      for (int j = 0; j < 4; j++) acc[i][j] = mfma16(a[i], b[j], acc[i][j]);
    __syncthreads();
  }

#pragma unroll
  for (int i = 0; i < 4; i++)
#pragma unroll
    for (int r = 0; r < 4; r++) {
      int rt = wm * 64 + 16 * i + quad * 4 + r;
      int lrow = rowbase + rt;
      if (lrow < cnt) {
        int t = row2token[off + lrow];
        float cw = roww[off + lrow];
#pragma unroll
        for (int j = 0; j < 4; j++) {
          int h = ntile * 128 + wn * 64 + 16 * j + m;
          atomicAdd(out + (size_t)t * H_DIM + h, cw * acc[i][j][r]);
        }
      }
    }
}

// ---------------- host ----------------

extern "C" void kernel_launch(void* const* d_in, const int* in_sizes, int n_in,
                              void* d_out, int out_size, void* d_ws, size_t ws_size,
                              hipStream_t stream) {
  const float* x  = (const float*)d_in[0];
  const float* rw = (const float*)d_in[1];
  const float* wg = (const float*)d_in[2];
  const float* wu = (const float*)d_in[3];
  const float* wd = (const float*)d_in[4];
  float* out = (float*)d_out;

  char* ws = (char*)d_ws;
  size_t p = 0;
  auto alloc = [&](size_t bytes) {
    char* r = ws + p;
    p = (p + bytes + 255) & ~(size_t)255;
    return r;
  };
  unsigned short* Xb  = (unsigned short*)alloc((size_t)T_TOK * H_DIM * 2);
  unsigned short* Wgt = (unsigned short*)alloc((size_t)E_NUM * F_DIM * H_DIM * 2);
  unsigned short* Wut = (unsigned short*)alloc((size_t)E_NUM * F_DIM * H_DIM * 2);
  unsigned short* Wdt = (unsigned short*)alloc((size_t)E_NUM * H_DIM * F_DIM * 2);
  unsigned short* Act = (unsigned short*)alloc((size_t)ROWS_CAP * F_DIM * 2);
  int*   t2i = (int*)alloc(T_TOK * 2 * 4);
  float* t2w = (float*)alloc(T_TOK * 2 * 4);
  int*   row2token = (int*)alloc(ROWS_CAP * 4);
  float* roww = (float*)alloc(ROWS_CAP * 4);
  int* ctrs = (int*)alloc(64 * 4);
  int* counts  = ctrs;        // 8
  int* cursors = ctrs + 8;    // 8
  float* psum  = (float*)(ctrs + 16);  // 8
  int* offsets = ctrs + 24;   // 9

  hipMemsetAsync(out, 0, (size_t)T_TOK * H_DIM * 4, stream);
  hipMemsetAsync(ctrs, 0, 96, stream);

  conv_x_kernel<<<T_TOK * H_DIM / 4 / 256, 256, 0, stream>>>(x, Xb);
  transpose_conv<<<dim3(F_DIM / 32, H_DIM / 32, E_NUM), dim3(32, 8), 0, stream>>>(wg, Wgt, H_DIM, F_DIM);
  transpose_conv<<<dim3(F_DIM / 32, H_DIM / 32, E_NUM), dim3(32, 8), 0, stream>>>(wu, Wut, H_DIM, F_DIM);
  transpose_conv<<<dim3(H_DIM / 32, F_DIM / 32, E_NUM), dim3(32, 8), 0, stream>>>(wd, Wdt, F_DIM, H_DIM);

  router_kernel<<<T_TOK / 64, 256, 0, stream>>>(x, rw, t2i, t2w, counts, psum);
  scan_aux_kernel<<<1, 64, 0, stream>>>(counts, psum, offsets, cursors, out + (size_t)T_TOK * H_DIM);
  assign_kernel<<<T_TOK / 256, 256, 0, stream>>>(t2i, t2w, cursors, row2token, roww);

  gateup_kernel<<<dim3(TOTAL_MT, F_DIM / 64), 256, 0, stream>>>(Xb, Wgt, Wut, Act, counts, offsets, row2token);
  down_kernel<<<dim3(TOTAL_MT, H_DIM / 128), 256, 0, stream>>>(Act, Wdt, counts, offsets, row2token, roww, out);
}

// Round 3
// 708.100 us; speedup vs baseline: 1.6032x; 1.0187x over previous
//
#include <hip/hip_runtime.h>
#include <hip/hip_bf16.h>
#include <stdint.h>

// Problem constants
#define T_TOK 4096   // B*S
#define H_DIM 1024
#define F_DIM 2816
#define E_NUM 8
#define ROWS_CAP 9216   // 8192 + 8*128 padding headroom
#define TOTAL_MT 72     // ROWS_CAP / 128

typedef float  f32x4  __attribute__((ext_vector_type(4)));
typedef __bf16 bf16x8 __attribute__((ext_vector_type(8)));

__device__ __forceinline__ unsigned short f32_bf16(float f) {
  union { float f; unsigned u; } v; v.f = f;
  unsigned r = v.u + 0x7fffu + ((v.u >> 16) & 1u);
  return (unsigned short)(r >> 16);
}

__device__ __forceinline__ void async16(const void* g, void* l) {
  __builtin_amdgcn_global_load_lds(
      (__attribute__((address_space(1))) void*)(g),
      (__attribute__((address_space(3))) void*)(l),
      16, 0, 0);
}

__device__ __forceinline__ f32x4 mfma16(bf16x8 a, bf16x8 b, f32x4 c) {
  return __builtin_amdgcn_mfma_f32_16x16x32_bf16(a, b, c, 0, 0, 0);
}

// ---------------- converts ----------------

// x fp32 [T,H] -> bf16 [T,H]
__global__ __launch_bounds__(256) void conv_x_kernel(const float* __restrict__ x,
                                                     unsigned short* __restrict__ xb) {
  int i = blockIdx.x * 256 + threadIdx.x;   // one float4 per thread
  float4 v = ((const float4*)x)[i];
  ushort4 o;
  o.x = f32_bf16(v.x); o.y = f32_bf16(v.y); o.z = f32_bf16(v.z); o.w = f32_bf16(v.w);
  ((ushort4*)xb)[i] = o;
}

// Unified transpose+convert: z selects {wg,wu,wd} x expert.
// src [R][C] fp32 -> dst [C][R] bf16, 64x64 tiles.
__global__ __launch_bounds__(256) void transpose_all(const float* __restrict__ wg,
                                                     const float* __restrict__ wu,
                                                     const float* __restrict__ wd,
                                                     unsigned short* __restrict__ Wgt,
                                                     unsigned short* __restrict__ Wut,
                                                     unsigned short* __restrict__ Wdt) {
  int mz = blockIdx.z >> 3, e = blockIdx.z & 7;
  const float* s; unsigned short* d; int R, C;
  size_t mat = (size_t)H_DIM * F_DIM;
  if (mz == 0)      { s = wg + e * mat; d = Wgt + e * mat; R = H_DIM; C = F_DIM; }
  else if (mz == 1) { s = wu + e * mat; d = Wut + e * mat; R = H_DIM; C = F_DIM; }
  else              { s = wd + e * mat; d = Wdt + e * mat; R = F_DIM; C = H_DIM; }
  int c0 = blockIdx.x * 64, r0 = blockIdx.y * 64;
  if (c0 >= C || r0 >= R) return;

  __shared__ float tile[64 * 65];
  int tid = threadIdx.x;
  int rr = tid >> 4, c4 = tid & 15;
#pragma unroll
  for (int it = 0; it < 4; it++) {
    int r = rr + 16 * it;
    float4 v = *(const float4*)(s + (size_t)(r0 + r) * C + c0 + c4 * 4);
    tile[r * 65 + c4 * 4 + 0] = v.x;
    tile[r * 65 + c4 * 4 + 1] = v.y;
    tile[r * 65 + c4 * 4 + 2] = v.z;
    tile[r * 65 + c4 * 4 + 3] = v.w;
  }
  __syncthreads();
  int cc = tid >> 4, r4 = tid & 15;
#pragma unroll
  for (int it = 0; it < 4; it++) {
    int c = cc + 16 * it;
    ushort4 o;
    o.x = f32_bf16(tile[(r4 * 4 + 0) * 65 + c]);
    o.y = f32_bf16(tile[(r4 * 4 + 1) * 65 + c]);
    o.z = f32_bf16(tile[(r4 * 4 + 2) * 65 + c]);
    o.w = f32_bf16(tile[(r4 * 4 + 3) * 65 + c]);
    *(ushort4*)(d + (size_t)(c0 + c) * R + r0 + r4 * 4) = o;
  }
}

// ---------------- router ----------------

__global__ __launch_bounds__(256) void router_kernel(const float* __restrict__ x,
                                                     const float* __restrict__ rw,
                                                     int* __restrict__ t2i,
                                                     float* __restrict__ t2w,
                                                     int* __restrict__ counts,
                                                     float* __restrict__ psum) {
  __shared__ float srw[E_NUM * H_DIM];  // 32 KB
  __shared__ float sP[E_NUM];
  __shared__ int sC[E_NUM];
  int tid = threadIdx.x;
  for (int i = tid; i < E_NUM * H_DIM; i += 256) srw[i] = rw[i];
  if (tid < E_NUM) { sP[tid] = 0.f; sC[tid] = 0; }
  __syncthreads();
  int w = tid >> 6, lane = tid & 63;
  for (int it = 0; it < 4; ++it) {
    int t = blockIdx.x * 16 + w * 4 + it;
    float acc[E_NUM];
#pragma unroll
    for (int e = 0; e < E_NUM; e++) acc[e] = 0.f;
    const float* xr = x + (size_t)t * H_DIM;
    for (int h = lane; h < H_DIM; h += 64) {
      float xv = xr[h];
#pragma unroll
      for (int e = 0; e < E_NUM; e++) acc[e] += xv * srw[e * H_DIM + h];
    }
#pragma unroll
    for (int e = 0; e < E_NUM; e++) {
      float v = acc[e];
      for (int o = 32; o > 0; o >>= 1) v += __shfl_down(v, o, 64);
      acc[e] = __shfl(v, 0, 64);
    }
    if (lane == 0) {
      float mx = acc[0];
#pragma unroll
      for (int e = 1; e < E_NUM; e++) mx = fmaxf(mx, acc[e]);
      float pr[E_NUM], s = 0.f;
#pragma unroll
      for (int e = 0; e < E_NUM; e++) { pr[e] = __expf(acc[e] - mx); s += pr[e]; }
      float inv = 1.f / s;
#pragma unroll
      for (int e = 0; e < E_NUM; e++) atomicAdd(&sP[e], pr[e] * inv);
      int i0 = 0; float v0 = acc[0];
#pragma unroll
      for (int e = 1; e < E_NUM; e++) if (acc[e] > v0) { v0 = acc[e]; i0 = e; }
      int i1 = -1; float v1 = -3.4e38f;
#pragma unroll
      for (int e = 0; e < E_NUM; e++) if (e != i0 && acc[e] > v1) { v1 = acc[e]; i1 = e; }
      float e1 = __expf(v1 - v0);
      float w0 = 1.f / (1.f + e1);
      t2i[2 * t] = i0; t2i[2 * t + 1] = i1;
      t2w[2 * t] = w0; t2w[2 * t + 1] = e1 * w0;
      atomicAdd(&sC[i0], 1); atomicAdd(&sC[i1], 1);
    }
  }
  __syncthreads();
  if (tid < E_NUM) { atomicAdd(&counts[tid], sC[tid]); atomicAdd(&psum[tid], sP[tid]); }
}

__global__ void scan_aux_kernel(const int* __restrict__ counts, const float* __restrict__ psum,
                                int* __restrict__ offsets, int* __restrict__ cursors,
                                float* __restrict__ aux_out) {
  if (threadIdx.x == 0 && blockIdx.x == 0) {
    int off = 0; float aux = 0.f;
    for (int e = 0; e < E_NUM; e++) {
      offsets[e] = off;
      cursors[e] = off;
      off += (counts[e] + 127) & ~127;
      aux += ((float)counts[e] / 8192.0f) * (psum[e] / 4096.0f);
    }
    offsets[E_NUM] = off;
    *aux_out = 8.0f * aux;
  }
}

__global__ __launch_bounds__(256) void assign_kernel(const int* __restrict__ t2i,
                                                     const float* __restrict__ t2w,
                                                     int* __restrict__ cursors,
                                                     int* __restrict__ row2token,
                                                     float* __restrict__ roww,
                                                     int* __restrict__ t2row) {
  int t = blockIdx.x * 256 + threadIdx.x;
#pragma unroll
  for (int s = 0; s < 2; s++) {
    int e = t2i[2 * t + s];
    int p = atomicAdd(&cursors[e], 1);
    row2token[p] = t;
    roww[p] = t2w[2 * t + s];
    t2row[2 * t + s] = p;
  }
}

// Map a global (padded) row-tile index to its expert via offsets[].
__device__ __forceinline__ int find_expert(const int* __restrict__ offsets, int row0,
                                           int& off_out) {
  int esel = -1, off = 0;
#pragma unroll
  for (int e = 0; e < E_NUM; e++) {
    int lo = offsets[e], hi = offsets[e + 1];
    if (row0 >= lo && row0 < hi) { esel = e; off = lo; }
  }
  off_out = off;
  return esel;
}

// ---------------- fused gate/up GEMM ----------------
// act[row, f] = silu(x@Wg) * (x@Wu), bf16.  BM=128, BN=128 (dual acc), BK=32.
// Per k-step per wave: 32 MFMA : 12 ds_read_b128.
__global__ __launch_bounds__(256) void gateup_kernel(
    const unsigned short* __restrict__ xb,
    const unsigned short* __restrict__ wgt,
    const unsigned short* __restrict__ wut,
    unsigned short* __restrict__ act,
    const int* __restrict__ counts, const int* __restrict__ offsets,
    const int* __restrict__ row2token) {
  int g = blockIdx.x;
  int row0 = g * 128;
  int off;
  int e = find_expert(offsets, row0, off);
  if (e < 0) return;
  int cnt = counts[e];
  int rowbase = row0 - off;
  int ntile = blockIdx.y;  // F/128 = 22

  __shared__ __align__(16) unsigned short smA[128 * 32];
  __shared__ __align__(16) unsigned short smG[128 * 32];
  __shared__ __align__(16) unsigned short smU[128 * 32];

  int tid = threadIdx.x;
  int w = tid >> 6, lane = tid & 63;
  int wm = w & 1, wn = w >> 1;  // wave tile 64x64 of the 128x128 block tile

  // staging: each array has 512 x 16B chunks; thread handles chunk tid and tid+256
  int r0 = tid >> 2, q0 = tid & 3;
  int r1 = r0 + 64;
  int tok0 = (rowbase + r0 < cnt) ? row2token[off + rowbase + r0] : 0;
  int tok1 = (rowbase + r1 < cnt) ? row2token[off + rowbase + r1] : 0;
  const unsigned short* gA0 = xb + (size_t)tok0 * H_DIM + q0 * 8;
  const unsigned short* gA1 = xb + (size_t)tok1 * H_DIM + q0 * 8;
  size_t wb = (size_t)e * F_DIM * H_DIM;
  const unsigned short* gG0 = wgt + wb + (size_t)(ntile * 128 + r0) * H_DIM + q0 * 8;
  const unsigned short* gG1 = wgt + wb + (size_t)(ntile * 128 + r1) * H_DIM + q0 * 8;
  const unsigned short* gU0 = wut + wb + (size_t)(ntile * 128 + r0) * H_DIM + q0 * 8;
  const unsigned short* gU1 = wut + wb + (size_t)(ntile * 128 + r1) * H_DIM + q0 * 8;
  unsigned short* lA0 = smA + tid * 8;
  unsigned short* lA1 = smA + (tid + 256) * 8;
  unsigned short* lG0 = smG + tid * 8;
  unsigned short* lG1 = smG + (tid + 256) * 8;
  unsigned short* lU0 = smU + tid * 8;
  unsigned short* lU1 = smU + (tid + 256) * 8;

  f32x4 accg[4][4], accu[4][4];
#pragma unroll
  for (int i = 0; i < 4; i++)
#pragma unroll
    for (int j = 0; j < 4; j++) {
      accg[i][j] = (f32x4){0.f, 0.f, 0.f, 0.f};
      accu[i][j] = (f32x4){0.f, 0.f, 0.f, 0.f};
    }

  int m = lane & 15, quad = lane >> 4;
  for (int k0 = 0; k0 < H_DIM; k0 += 32) {
    async16(gA0 + k0, lA0);
    async16(gA1 + k0, lA1);
    async16(gG0 + k0, lG0);
    async16(gG1 + k0, lG1);
    async16(gU0 + k0, lU0);
    async16(gU1 + k0, lU1);
    __syncthreads();
    bf16x8 a[4], bg[4], bu[4];
#pragma unroll
    for (int i = 0; i < 4; i++)
      a[i] = *(const bf16x8*)(smA + (wm * 64 + 16 * i + m) * 32 + quad * 8);
#pragma unroll
    for (int j = 0; j < 4; j++) {
      bg[j] = *(const bf16x8*)(smG + (wn * 64 + 16 * j + m) * 32 + quad * 8);
      bu[j] = *(const bf16x8*)(smU + (wn * 64 + 16 * j + m) * 32 + quad * 8);
    }
#pragma unroll
    for (int i = 0; i < 4; i++)
#pragma unroll
      for (int j = 0; j < 4; j++) {
        accg[i][j] = mfma16(a[i], bg[j], accg[i][j]);
        accu[i][j] = mfma16(a[i], bu[j], accu[i][j]);
      }
    __syncthreads();
  }

  // epilogue: act = silu(g)*u
#pragma unroll
  for (int i = 0; i < 4; i++)
#pragma unroll
    for (int j = 0; j < 4; j++)
#pragma unroll
      for (int r = 0; r < 4; r++) {
        int rt = wm * 64 + 16 * i + quad * 4 + r;
        int ct = wn * 64 + 16 * j + m;
        float g2 = accg[i][j][r], u = accu[i][j][r];
        float sv = g2 / (1.f + __expf(-g2)) * u;
        act[(size_t)(off + rowbase + rt) * F_DIM + ntile * 128 + ct] = f32_bf16(sv);
      }
}

// ---------------- down GEMM -> Y scratch (no atomics) ----------------
// Y[row, h] = w_row * (act @ Wd).  BM=128, BN=128, BK=32.
__global__ __launch_bounds__(256) void down_kernel(
    const unsigned short* __restrict__ act,
    const unsigned short* __restrict__ wdt,   // [E][H][F] k-contig
    const int* __restrict__ counts, const int* __restrict__ offsets,
    const float* __restrict__ roww,
    float* __restrict__ Y) {
  int g = blockIdx.x;
  int row0 = g * 128;
  int off;
  int e = find_expert(offsets, row0, off);
  if (e < 0) return;
  int cnt = counts[e];
  int rowbase = row0 - off;
  int ntile = blockIdx.y;  // H/128 = 8

  __shared__ __align__(16) unsigned short smA[128 * 32];
  __shared__ __align__(16) unsigned short smB[128 * 32];

  int tid = threadIdx.x;
  int w = tid >> 6, lane = tid & 63;
  int wm = w & 1, wn = w >> 1;  // wave tile 64x64

  int r0 = tid >> 2, q0 = tid & 3;
  int r1 = r0 + 64;
  const unsigned short* gA0 = act + (size_t)(off + rowbase + r0) * F_DIM + q0 * 8;
  const unsigned short* gA1 = act + (size_t)(off + rowbase + r1) * F_DIM + q0 * 8;
  size_t wb = (size_t)e * H_DIM * F_DIM;
  const unsigned short* gB0 = wdt + wb + (size_t)(ntile * 128 + r0) * F_DIM + q0 * 8;
  const unsigned short* gB1 = wdt + wb + (size_t)(ntile * 128 + r1) * F_DIM + q0 * 8;
  unsigned short* lA0 = smA + tid * 8;
  unsigned short* lA1 = smA + (tid + 256) * 8;
  unsigned short* lB0 = smB + tid * 8;
  unsigned short* lB1 = smB + (tid + 256) * 8;

  f32x4 acc[4][4];
#pragma unroll
  for (int i = 0; i < 4; i++)
#pragma unroll
    for (int j = 0; j < 4; j++) acc[i][j] = (f32x4){0.f, 0.f, 0.f, 0.f};

  int m = lane & 15, quad = lane >> 4;
  for (int k0 = 0; k0 < F_DIM; k0 += 32) {
    async16(gA0 + k0, lA0);
    async16(gA1 + k0, lA1);
    async16(gB0 + k0, lB0);
    async16(gB1 + k0, lB1);
    __syncthreads();
    bf16x8 a[4], b[4];
#pragma unroll
    for (int i = 0; i < 4; i++) {
      a[i] = *(const bf16x8*)(smA + (wm * 64 + 16 * i + m) * 32 + quad * 8);
      b[i] = *(const bf16x8*)(smB + (wn * 64 + 16 * i + m) * 32 + quad * 8);
    }
#pragma unroll
    for (int i = 0; i < 4; i++)
#pragma unroll
      for (int j = 0; j < 4; j++) acc[i][j] = mfma16(a[i], b[j], acc[i][j]);
    __syncthreads();
  }

#pragma unroll
  for (int i = 0; i < 4; i++)
#pragma unroll
    for (int r = 0; r < 4; r++) {
      int rt = wm * 64 + 16 * i + quad * 4 + r;
      int lrow = rowbase + rt;
      if (lrow < cnt) {
        float cw = roww[off + lrow];
#pragma unroll
        for (int j = 0; j < 4; j++) {
          int h = ntile * 128 + wn * 64 + 16 * j + m;
          Y[(size_t)(off + lrow) * H_DIM + h] = cw * acc[i][j][r];
        }
      }
    }
}

// out[t] = Y[row(t,0)] + Y[row(t,1)]; one block per token (256 float4 = 1024 floats)
__global__ __launch_bounds__(256) void combine_kernel(const float* __restrict__ Y,
                                                      const int* __restrict__ t2row,
                                                      float* __restrict__ out) {
  int t = blockIdx.x, hc = threadIdx.x;
  int r0 = t2row[2 * t], r1 = t2row[2 * t + 1];
  float4 a = ((const float4*)(Y + (size_t)r0 * H_DIM))[hc];
  float4 b = ((const float4*)(Y + (size_t)r1 * H_DIM))[hc];
  float4 o; o.x = a.x + b.x; o.y = a.y + b.y; o.z = a.z + b.z; o.w = a.w + b.w;
  ((float4*)(out + (size_t)t * H_DIM))[hc] = o;
}

// ---------------- host ----------------

extern "C" void kernel_launch(void* const* d_in, const int* in_sizes, int n_in,
                              void* d_out, int out_size, void* d_ws, size_t ws_size,
                              hipStream_t stream) {
  const float* x  = (const float*)d_in[0];
  const float* rw = (const float*)d_in[1];
  const float* wg = (const float*)d_in[2];
  const float* wu = (const float*)d_in[3];
  const float* wd = (const float*)d_in[4];
  float* out = (float*)d_out;

  char* ws = (char*)d_ws;
  size_t p = 0;
  auto alloc = [&](size_t bytes) {
    char* r = ws + p;
    p = (p + bytes + 255) & ~(size_t)255;
    return r;
  };
  unsigned short* Xb  = (unsigned short*)alloc((size_t)T_TOK * H_DIM * 2);
  unsigned short* Wgt = (unsigned short*)alloc((size_t)E_NUM * F_DIM * H_DIM * 2);
  unsigned short* Wut = (unsigned short*)alloc((size_t)E_NUM * F_DIM * H_DIM * 2);
  unsigned short* Wdt = (unsigned short*)alloc((size_t)E_NUM * H_DIM * F_DIM * 2);
  unsigned short* Act = (unsigned short*)alloc((size_t)ROWS_CAP * F_DIM * 2);
  int*   t2i = (int*)alloc(T_TOK * 2 * 4);
  float* t2w = (float*)alloc(T_TOK * 2 * 4);
  int*   t2row = (int*)alloc(T_TOK * 2 * 4);
  int*   row2token = (int*)alloc(ROWS_CAP * 4);
  float* roww = (float*)alloc(ROWS_CAP * 4);
  int* ctrs = (int*)alloc(64 * 4);
  int* counts  = ctrs;        // 8
  int* cursors = ctrs + 8;    // 8
  float* psum  = (float*)(ctrs + 16);  // 8
  int* offsets = ctrs + 24;   // 9
  // Y overlays Wgt (dead after gateup): 9216*1024*4 = 37.75 MB <= 46.1 MB
  float* Y = (float*)Wgt;

  hipMemsetAsync(ctrs, 0, 96, stream);

  conv_x_kernel<<<T_TOK * H_DIM / 4 / 256, 256, 0, stream>>>(x, Xb);
  transpose_all<<<dim3(F_DIM / 64, F_DIM / 64, 24), 256, 0, stream>>>(wg, wu, wd, Wgt, Wut, Wdt);

  router_kernel<<<T_TOK / 16, 256, 0, stream>>>(x, rw, t2i, t2w, counts, psum);
  scan_aux_kernel<<<1, 64, 0, stream>>>(counts, psum, offsets, cursors, out + (size_t)T_TOK * H_DIM);
  assign_kernel<<<T_TOK / 256, 256, 0, stream>>>(t2i, t2w, cursors, row2token, roww, t2row);

  gateup_kernel<<<dim3(TOTAL_MT, F_DIM / 128), 256, 0, stream>>>(Xb, Wgt, Wut, Act, counts, offsets, row2token);
  down_kernel<<<dim3(TOTAL_MT, H_DIM / 128), 256, 0, stream>>>(Act, Wdt, counts, offsets, roww, Y);
  combine_kernel<<<T_TOK, 256, 0, stream>>>(Y, t2row, out);
}

// Round 4
// 626.176 us; speedup vs baseline: 1.8129x; 1.1308x over previous
//
#include <hip/hip_runtime.h>
#include <hip/hip_bf16.h>
#include <stdint.h>

// Problem constants
#define T_TOK 4096   // B*S
#define H_DIM 1024
#define F_DIM 2816
#define E_NUM 8
#define ROWS_CAP 9216   // 8192 + 8*128 padding headroom
#define TOTAL_MT 72     // ROWS_CAP / 128

typedef float  f32x4  __attribute__((ext_vector_type(4)));
typedef __bf16 bf16x8 __attribute__((ext_vector_type(8)));

__device__ __forceinline__ unsigned short f32_bf16(float f) {
  union { float f; unsigned u; } v; v.f = f;
  unsigned r = v.u + 0x7fffu + ((v.u >> 16) & 1u);
  return (unsigned short)(r >> 16);
}

__device__ __forceinline__ void async16(const void* g, void* l) {
  __builtin_amdgcn_global_load_lds(
      (__attribute__((address_space(1))) void*)(g),
      (__attribute__((address_space(3))) void*)(l),
      16, 0, 0);
}

__device__ __forceinline__ f32x4 mfma16(bf16x8 a, bf16x8 b, f32x4 c) {
  return __builtin_amdgcn_mfma_f32_16x16x32_bf16(a, b, c, 0, 0, 0);
}

// ---------------- converts ----------------

// x fp32 [T,H] -> bf16 [T,H]
__global__ __launch_bounds__(256) void conv_x_kernel(const float* __restrict__ x,
                                                     unsigned short* __restrict__ xb) {
  int i = blockIdx.x * 256 + threadIdx.x;   // one float4 per thread
  float4 v = ((const float4*)x)[i];
  ushort4 o;
  o.x = f32_bf16(v.x); o.y = f32_bf16(v.y); o.z = f32_bf16(v.z); o.w = f32_bf16(v.w);
  ((ushort4*)xb)[i] = o;
}

// Unified transpose+convert, FLAT grid: exactly 3*704 live 64x64 tiles.
// src [R][C] fp32 -> dst [C][R] bf16.
__global__ __launch_bounds__(256) void transpose_all(const float* __restrict__ wg,
                                                     const float* __restrict__ wu,
                                                     const float* __restrict__ wd,
                                                     unsigned short* __restrict__ Wgt,
                                                     unsigned short* __restrict__ Wut,
                                                     unsigned short* __restrict__ Wdt) {
  int bx = blockIdx.x;            // [0, 2112)
  int mz = bx / 704, local = bx % 704;
  const float* s; unsigned short* d; int R, C, tx;
  size_t mat = (size_t)H_DIM * F_DIM;
  if (mz == 0)      { s = wg; d = Wgt; R = H_DIM; C = F_DIM; tx = 44; }
  else if (mz == 1) { s = wu; d = Wut; R = H_DIM; C = F_DIM; tx = 44; }
  else              { s = wd; d = Wdt; R = F_DIM; C = H_DIM; tx = 16; }
  // expert folded into row index: treat as one [E*R][C] matrix, transpose per 64-tile.
  // Tiles never straddle experts since R is a multiple of 64.
  int c0 = (local % tx) * 64;
  int rg0 = (local / tx) * 64;          // global row across all experts? No: per matrix per expert.
  // local/tx in [0, 704/tx) = [0,16) for mz0/1 (R/64=16), [0,44) for mz2 (R/64=44).
  // But we must also cover E_NUM experts: fold expert into grid via blockIdx.y.
  int e = blockIdx.y;
  s += e * mat; d += e * mat;
  int r0 = rg0;

  __shared__ float tile[64 * 65];
  int tid = threadIdx.x;
  int rr = tid >> 4, c4 = tid & 15;
#pragma unroll
  for (int it = 0; it < 4; it++) {
    int r = rr + 16 * it;
    float4 v = *(const float4*)(s + (size_t)(r0 + r) * C + c0 + c4 * 4);
    tile[r * 65 + c4 * 4 + 0] = v.x;
    tile[r * 65 + c4 * 4 + 1] = v.y;
    tile[r * 65 + c4 * 4 + 2] = v.z;
    tile[r * 65 + c4 * 4 + 3] = v.w;
  }
  __syncthreads();
  int cc = tid >> 4, r4 = tid & 15;
#pragma unroll
  for (int it = 0; it < 4; it++) {
    int c = cc + 16 * it;
    ushort4 o;
    o.x = f32_bf16(tile[(r4 * 4 + 0) * 65 + c]);
    o.y = f32_bf16(tile[(r4 * 4 + 1) * 65 + c]);
    o.z = f32_bf16(tile[(r4 * 4 + 2) * 65 + c]);
    o.w = f32_bf16(tile[(r4 * 4 + 3) * 65 + c]);
    *(ushort4*)(d + (size_t)(c0 + c) * R + r0 + r4 * 4) = o;
  }
}

// ---------------- router ----------------

__global__ __launch_bounds__(256) void router_kernel(const float* __restrict__ x,
                                                     const float* __restrict__ rw,
                                                     int* __restrict__ t2i,
                                                     float* __restrict__ t2w,
                                                     int* __restrict__ counts,
                                                     float* __restrict__ psum) {
  __shared__ float srw[E_NUM * H_DIM];  // 32 KB
  __shared__ float sP[E_NUM];
  __shared__ int sC[E_NUM];
  int tid = threadIdx.x;
  for (int i = tid; i < E_NUM * H_DIM; i += 256) srw[i] = rw[i];
  if (tid < E_NUM) { sP[tid] = 0.f; sC[tid] = 0; }
  __syncthreads();
  int w = tid >> 6, lane = tid & 63;
  for (int it = 0; it < 4; ++it) {
    int t = blockIdx.x * 16 + w * 4 + it;
    float acc[E_NUM];
#pragma unroll
    for (int e = 0; e < E_NUM; e++) acc[e] = 0.f;
    const float* xr = x + (size_t)t * H_DIM;
    for (int h = lane; h < H_DIM; h += 64) {
      float xv = xr[h];
#pragma unroll
      for (int e = 0; e < E_NUM; e++) acc[e] += xv * srw[e * H_DIM + h];
    }
#pragma unroll
    for (int e = 0; e < E_NUM; e++) {
      float v = acc[e];
      for (int o = 32; o > 0; o >>= 1) v += __shfl_down(v, o, 64);
      acc[e] = __shfl(v, 0, 64);
    }
    if (lane == 0) {
      float mx = acc[0];
#pragma unroll
      for (int e = 1; e < E_NUM; e++) mx = fmaxf(mx, acc[e]);
      float pr[E_NUM], s = 0.f;
#pragma unroll
      for (int e = 0; e < E_NUM; e++) { pr[e] = __expf(acc[e] - mx); s += pr[e]; }
      float inv = 1.f / s;
#pragma unroll
      for (int e = 0; e < E_NUM; e++) atomicAdd(&sP[e], pr[e] * inv);
      int i0 = 0; float v0 = acc[0];
#pragma unroll
      for (int e = 1; e < E_NUM; e++) if (acc[e] > v0) { v0 = acc[e]; i0 = e; }
      int i1 = -1; float v1 = -3.4e38f;
#pragma unroll
      for (int e = 0; e < E_NUM; e++) if (e != i0 && acc[e] > v1) { v1 = acc[e]; i1 = e; }
      float e1 = __expf(v1 - v0);
      float w0 = 1.f / (1.f + e1);
      t2i[2 * t] = i0; t2i[2 * t + 1] = i1;
      t2w[2 * t] = w0; t2w[2 * t + 1] = e1 * w0;
      atomicAdd(&sC[i0], 1); atomicAdd(&sC[i1], 1);
    }
  }
  __syncthreads();
  if (tid < E_NUM) { atomicAdd(&counts[tid], sC[tid]); atomicAdd(&psum[tid], sP[tid]); }
}

__global__ void scan_aux_kernel(const int* __restrict__ counts, const float* __restrict__ psum,
                                int* __restrict__ offsets, int* __restrict__ cursors,
                                float* __restrict__ aux_out) {
  if (threadIdx.x == 0 && blockIdx.x == 0) {
    int off = 0; float aux = 0.f;
    for (int e = 0; e < E_NUM; e++) {
      offsets[e] = off;
      cursors[e] = off;
      off += (counts[e] + 127) & ~127;
      aux += ((float)counts[e] / 8192.0f) * (psum[e] / 4096.0f);
    }
    offsets[E_NUM] = off;
    *aux_out = 8.0f * aux;
  }
}

__global__ __launch_bounds__(256) void assign_kernel(const int* __restrict__ t2i,
                                                     const float* __restrict__ t2w,
                                                     int* __restrict__ cursors,
                                                     int* __restrict__ row2token,
                                                     float* __restrict__ roww,
                                                     int* __restrict__ t2row) {
  int t = blockIdx.x * 256 + threadIdx.x;
#pragma unroll
  for (int s = 0; s < 2; s++) {
    int e = t2i[2 * t + s];
    int p = atomicAdd(&cursors[e], 1);
    row2token[p] = t;
    roww[p] = t2w[2 * t + s];
    t2row[2 * t + s] = p;
  }
}

// Map a global (padded) row-tile index to its expert via offsets[].
__device__ __forceinline__ int find_expert(const int* __restrict__ offsets, int row0,
                                           int& off_out) {
  int esel = -1, off = 0;
#pragma unroll
  for (int e = 0; e < E_NUM; e++) {
    int lo = offsets[e], hi = offsets[e + 1];
    if (row0 >= lo && row0 < hi) { esel = e; off = lo; }
  }
  off_out = off;
  return esel;
}

// ---------------- fused gate/up GEMM ----------------
// act[row, f] = silu(x@Wg) * (x@Wu), bf16.  BM=128, BN=64, BK=32.
// VGPR 76 / occupancy ~28% config (round-2 verified 171 us @ ~590 TF).
// NOTE: BN=128 dual-acc variant regressed (VGPR 164 -> occupancy 10%).
__global__ __launch_bounds__(256) void gateup_kernel(
    const unsigned short* __restrict__ xb,
    const unsigned short* __restrict__ wgt,
    const unsigned short* __restrict__ wut,
    unsigned short* __restrict__ act,
    const int* __restrict__ counts, const int* __restrict__ offsets,
    const int* __restrict__ row2token) {
  int g = blockIdx.x;
  int row0 = g * 128;
  int off;
  int e = find_expert(offsets, row0, off);
  if (e < 0) return;
  int cnt = counts[e];
  int rowbase = row0 - off;
  int ntile = blockIdx.y;     // F/64 = 44

  __shared__ __align__(16) unsigned short smA[128 * 32];
  __shared__ __align__(16) unsigned short smG[64 * 32];
  __shared__ __align__(16) unsigned short smU[64 * 32];

  int tid = threadIdx.x;
  int w = tid >> 6, lane = tid & 63;
  int wm = w & 1, wn = w >> 1;  // wave tile 64x32 within 128x64

  int cA0 = w * 64 + lane;
  int rA0 = cA0 >> 2, qA0 = cA0 & 3;
  int rA1 = rA0 + 64;
  int tok0 = (rowbase + rA0 < cnt) ? row2token[off + rowbase + rA0] : 0;
  int tok1 = (rowbase + rA1 < cnt) ? row2token[off + rowbase + rA1] : 0;
  const unsigned short* gA0 = xb + (size_t)tok0 * H_DIM + qA0 * 8;
  const unsigned short* gA1 = xb + (size_t)tok1 * H_DIM + qA0 * 8;
  size_t wb = (size_t)e * F_DIM * H_DIM;
  const unsigned short* gG = wgt + wb + (size_t)(ntile * 64 + rA0) * H_DIM + qA0 * 8;
  const unsigned short* gU = wut + wb + (size_t)(ntile * 64 + rA0) * H_DIM + qA0 * 8;
  unsigned short* lA0 = smA + (w * 64) * 8;
  unsigned short* lA1 = smA + (256 + w * 64) * 8;
  unsigned short* lG = smG + (w * 64) * 8;
  unsigned short* lU = smU + (w * 64) * 8;

  f32x4 accg[4][2], accu[4][2];
#pragma unroll
  for (int i = 0; i < 4; i++)
#pragma unroll
    for (int j = 0; j < 2; j++) {
      accg[i][j] = (f32x4){0.f, 0.f, 0.f, 0.f};
      accu[i][j] = (f32x4){0.f, 0.f, 0.f, 0.f};
    }

  int m = lane & 15, quad = lane >> 4;
  for (int k0 = 0; k0 < H_DIM; k0 += 32) {
    async16(gA0 + k0, lA0);
    async16(gA1 + k0, lA1);
    async16(gG + k0, lG);
    async16(gU + k0, lU);
    __syncthreads();
    bf16x8 a[4], bg[2], bu[2];
#pragma unroll
    for (int i = 0; i < 4; i++)
      a[i] = *(const bf16x8*)(smA + (wm * 64 + 16 * i + m) * 32 + quad * 8);
#pragma unroll
    for (int j = 0; j < 2; j++) {
      bg[j] = *(const bf16x8*)(smG + (wn * 32 + 16 * j + m) * 32 + quad * 8);
      bu[j] = *(const bf16x8*)(smU + (wn * 32 + 16 * j + m) * 32 + quad * 8);
    }
#pragma unroll
    for (int i = 0; i < 4; i++)
#pragma unroll
      for (int j = 0; j < 2; j++) {
        accg[i][j] = mfma16(a[i], bg[j], accg[i][j]);
        accu[i][j] = mfma16(a[i], bu[j], accu[i][j]);
      }
    __syncthreads();
  }

#pragma unroll
  for (int i = 0; i < 4; i++)
#pragma unroll
    for (int j = 0; j < 2; j++)
#pragma unroll
      for (int r = 0; r < 4; r++) {
        int rt = wm * 64 + 16 * i + quad * 4 + r;
        int ct = wn * 32 + 16 * j + m;
        float g2 = accg[i][j][r], u = accu[i][j][r];
        float sv = g2 / (1.f + __expf(-g2)) * u;
        act[(size_t)(off + rowbase + rt) * F_DIM + ntile * 64 + ct] = f32_bf16(sv);
      }
}

// ---------------- down GEMM, split-k x2 -> Y scratch ----------------
// Y[ks][row, h] = w_row * (act[:, ks*1408:+1408] @ Wd[ks*1408:+1408, :]).
__global__ __launch_bounds__(256) void down_kernel(
    const unsigned short* __restrict__ act,
    const unsigned short* __restrict__ wdt,   // [E][H][F] k-contig
    const int* __restrict__ counts, const int* __restrict__ offsets,
    const float* __restrict__ roww,
    float* __restrict__ Y) {
  int g = blockIdx.x;
  int row0 = g * 128;
  int off;
  int e = find_expert(offsets, row0, off);
  if (e < 0) return;
  int cnt = counts[e];
  int rowbase = row0 - off;
  int ntile = blockIdx.y;  // H/128 = 8
  int ks = blockIdx.z;     // split-k slice
  int kbase = ks * (F_DIM / 2);

  __shared__ __align__(16) unsigned short smA[128 * 32];
  __shared__ __align__(16) unsigned short smB[128 * 32];

  int tid = threadIdx.x;
  int w = tid >> 6, lane = tid & 63;
  int wm = w & 1, wn = w >> 1;  // wave tile 64x64

  int r0 = tid >> 2, q0 = tid & 3;
  int r1 = r0 + 64;
  const unsigned short* gA0 = act + (size_t)(off + rowbase + r0) * F_DIM + kbase + q0 * 8;
  const unsigned short* gA1 = act + (size_t)(off + rowbase + r1) * F_DIM + kbase + q0 * 8;
  size_t wb = (size_t)e * H_DIM * F_DIM;
  const unsigned short* gB0 = wdt + wb + (size_t)(ntile * 128 + r0) * F_DIM + kbase + q0 * 8;
  const unsigned short* gB1 = wdt + wb + (size_t)(ntile * 128 + r1) * F_DIM + kbase + q0 * 8;
  unsigned short* lA0 = smA + tid * 8;
  unsigned short* lA1 = smA + (tid + 256) * 8;
  unsigned short* lB0 = smB + tid * 8;
  unsigned short* lB1 = smB + (tid + 256) * 8;

  f32x4 acc[4][4];
#pragma unroll
  for (int i = 0; i < 4; i++)
#pragma unroll
    for (int j = 0; j < 4; j++) acc[i][j] = (f32x4){0.f, 0.f, 0.f, 0.f};

  int m = lane & 15, quad = lane >> 4;
  for (int k0 = 0; k0 < F_DIM / 2; k0 += 32) {
    async16(gA0 + k0, lA0);
    async16(gA1 + k0, lA1);
    async16(gB0 + k0, lB0);
    async16(gB1 + k0, lB1);
    __syncthreads();
    bf16x8 a[4], b[4];
#pragma unroll
    for (int i = 0; i < 4; i++) {
      a[i] = *(const bf16x8*)(smA + (wm * 64 + 16 * i + m) * 32 + quad * 8);
      b[i] = *(const bf16x8*)(smB + (wn * 64 + 16 * i + m) * 32 + quad * 8);
    }
#pragma unroll
    for (int i = 0; i < 4; i++)
#pragma unroll
      for (int j = 0; j < 4; j++) acc[i][j] = mfma16(a[i], b[j], acc[i][j]);
    __syncthreads();
  }

  float* Yk = Y + (size_t)ks * ROWS_CAP * H_DIM;
#pragma unroll
  for (int i = 0; i < 4; i++)
#pragma unroll
    for (int r = 0; r < 4; r++) {
      int rt = wm * 64 + 16 * i + quad * 4 + r;
      int lrow = rowbase + rt;
      if (lrow < cnt) {
        float cw = roww[off + lrow];
#pragma unroll
        for (int j = 0; j < 4; j++) {
          int h = ntile * 128 + wn * 64 + 16 * j + m;
          Yk[(size_t)(off + lrow) * H_DIM + h] = cw * acc[i][j][r];
        }
      }
    }
}

// out[t] = sum over 2 rows x 2 k-slices of Y
__global__ __launch_bounds__(256) void combine_kernel(const float* __restrict__ Y,
                                                      const int* __restrict__ t2row,
                                                      float* __restrict__ out) {
  int t = blockIdx.x, hc = threadIdx.x;
  int r0 = t2row[2 * t], r1 = t2row[2 * t + 1];
  const float* Y1 = Y + (size_t)ROWS_CAP * H_DIM;
  float4 a = ((const float4*)(Y  + (size_t)r0 * H_DIM))[hc];
  float4 b = ((const float4*)(Y  + (size_t)r1 * H_DIM))[hc];
  float4 c = ((const float4*)(Y1 + (size_t)r0 * H_DIM))[hc];
  float4 d = ((const float4*)(Y1 + (size_t)r1 * H_DIM))[hc];
  float4 o;
  o.x = (a.x + b.x) + (c.x + d.x);
  o.y = (a.y + b.y) + (c.y + d.y);
  o.z = (a.z + b.z) + (c.z + d.z);
  o.w = (a.w + b.w) + (c.w + d.w);
  ((float4*)(out + (size_t)t * H_DIM))[hc] = o;
}

// ---------------- host ----------------

extern "C" void kernel_launch(void* const* d_in, const int* in_sizes, int n_in,
                              void* d_out, int out_size, void* d_ws, size_t ws_size,
                              hipStream_t stream) {
  const float* x  = (const float*)d_in[0];
  const float* rw = (const float*)d_in[1];
  const float* wg = (const float*)d_in[2];
  const float* wu = (const float*)d_in[3];
  const float* wd = (const float*)d_in[4];
  float* out = (float*)d_out;

  char* ws = (char*)d_ws;
  size_t p = 0;
  auto alloc = [&](size_t bytes) {
    char* r = ws + p;
    p = (p + bytes + 255) & ~(size_t)255;
    return r;
  };
  unsigned short* Xb  = (unsigned short*)alloc((size_t)T_TOK * H_DIM * 2);
  unsigned short* Wgt = (unsigned short*)alloc((size_t)E_NUM * F_DIM * H_DIM * 2);
  unsigned short* Wut = (unsigned short*)alloc((size_t)E_NUM * F_DIM * H_DIM * 2);
  unsigned short* Wdt = (unsigned short*)alloc((size_t)E_NUM * H_DIM * F_DIM * 2);
  unsigned short* Act = (unsigned short*)alloc((size_t)ROWS_CAP * F_DIM * 2);
  int*   t2i = (int*)alloc(T_TOK * 2 * 4);
  float* t2w = (float*)alloc(T_TOK * 2 * 4);
  int*   t2row = (int*)alloc(T_TOK * 2 * 4);
  int*   row2token = (int*)alloc(ROWS_CAP * 4);
  float* roww = (float*)alloc(ROWS_CAP * 4);
  int* ctrs = (int*)alloc(64 * 4);
  int* counts  = ctrs;        // 8
  int* cursors = ctrs + 8;    // 8
  float* psum  = (float*)(ctrs + 16);  // 8
  int* offsets = ctrs + 24;   // 9
  // Y (2 k-slices): 2*9216*1024*4 = 75.5 MB, overlays Wgt+Wut (92.3 MB, dead after gateup)
  float* Y = (float*)Wgt;

  hipMemsetAsync(ctrs, 0, 96, stream);

  conv_x_kernel<<<T_TOK * H_DIM / 4 / 256, 256, 0, stream>>>(x, Xb);
  transpose_all<<<dim3(2112, E_NUM), 256, 0, stream>>>(wg, wu, wd, Wgt, Wut, Wdt);

  router_kernel<<<T_TOK / 16, 256, 0, stream>>>(x, rw, t2i, t2w, counts, psum);
  scan_aux_kernel<<<1, 64, 0, stream>>>(counts, psum, offsets, cursors, out + (size_t)T_TOK * H_DIM);
  assign_kernel<<<T_TOK / 256, 256, 0, stream>>>(t2i, t2w, cursors, row2token, roww, t2row);

  gateup_kernel<<<dim3(TOTAL_MT, F_DIM / 64), 256, 0, stream>>>(Xb, Wgt, Wut, Act, counts, offsets, row2token);
  down_kernel<<<dim3(TOTAL_MT, H_DIM / 128, 2), 256, 0, stream>>>(Act, Wdt, counts, offsets, roww, Y);
  combine_kernel<<<T_TOK, 256, 0, stream>>>(Y, t2row, out);
}